// Round 1
// baseline (2997.680 us; speedup 1.0000x reference)
//
#include <hip/hip_runtime.h>
#include <hip/hip_bf16.h>
#include <cstdint>
#include <cstddef>

// ---------------------------------------------------------------------------
// Mixtral sparse MoE block, MI355X (gfx950).
//   inputs (fp32): hidden_states [B,S,2048], gate_w [8,2048],
//                  w1 [8,4096,2048], w3 [8,4096,2048], w2 [8,2048,4096]
//   outputs (fp32): final [B,S,2048] ++ router_logits [T,8]
// Strategy: fp32 router (exact top-2), bf16 MFMA expert GEMMs (fp32 accum),
// bucket-gathered A rows, dual-B GEMM1 with fused SiLU*mul, atomicAdd scatter.
// ---------------------------------------------------------------------------

#define HID 2048
#define FFN_ 4096
#define NEXP 8

typedef __attribute__((ext_vector_type(8))) short short8;
typedef __attribute__((ext_vector_type(4))) float f32x4;
typedef __attribute__((ext_vector_type(4))) unsigned short u16x4;

#define GPTR(p) ((const __attribute__((address_space(1))) void*)(p))
#define LPTR(p) ((__attribute__((address_space(3))) void*)(p))

__device__ __forceinline__ unsigned short f2bf(float f) {
  union { float f; unsigned int u; } v; v.f = f;
  unsigned int r = v.u + 0x7FFFu + ((v.u >> 16) & 1u);   // RNE
  return (unsigned short)(r >> 16);
}

// --------------------------- router ----------------------------------------
// One wave per token: 8 fp32 dot products (K=2048), butterfly reduce,
// exact top-2 (lowest-index tie-break like jax.lax.top_k),
// w0 = sigmoid(l0-l1) == p0/(p0+p1) of the softmax pair (denominator cancels).
__global__ void router_kernel(const float* __restrict__ x,
                              const float* __restrict__ gw,
                              float* __restrict__ logits,
                              int2* __restrict__ top_e,
                              float2* __restrict__ top_w,
                              int* __restrict__ counts, int T) {
  int gid  = blockIdx.x * blockDim.x + threadIdx.x;
  int t    = gid >> 6;
  int lane = gid & 63;
  if (t >= T) return;
  const f32x4* xr = (const f32x4*)(x + (size_t)t * HID);
  float acc[8] = {0.f,0.f,0.f,0.f,0.f,0.f,0.f,0.f};
  for (int i = lane; i < HID / 4; i += 64) {
    f32x4 xv = xr[i];
#pragma unroll
    for (int e = 0; e < 8; ++e) {
      f32x4 gv = ((const f32x4*)(gw + e * HID))[i];
      acc[e] += xv.x * gv.x + xv.y * gv.y + xv.z * gv.z + xv.w * gv.w;
    }
  }
#pragma unroll
  for (int off = 32; off > 0; off >>= 1)
#pragma unroll
    for (int e = 0; e < 8; ++e) acc[e] += __shfl_xor(acc[e], off, 64);
  if (lane == 0) {
    f32x4* lp = (f32x4*)(logits + (size_t)t * 8);
    f32x4 l0 = {acc[0], acc[1], acc[2], acc[3]};
    f32x4 l1 = {acc[4], acc[5], acc[6], acc[7]};
    lp[0] = l0; lp[1] = l1;
    int e0 = 0;
#pragma unroll
    for (int e = 1; e < 8; ++e) if (acc[e] > acc[e0]) e0 = e;
    int e1 = -1;
#pragma unroll
    for (int e = 0; e < 8; ++e) {
      if (e == e0) continue;
      if (e1 < 0 || acc[e] > acc[e1]) e1 = e;
    }
    float w0 = 1.f / (1.f + expf(acc[e1] - acc[e0]));
    int2 te; te.x = e0; te.y = e1;
    float2 tw; tw.x = w0; tw.y = 1.f - w0;
    top_e[t] = te; top_w[t] = tw;
    atomicAdd(&counts[e0], 1);
    atomicAdd(&counts[e1], 1);
  }
}

// --------------------------- scan ------------------------------------------
__global__ void scan_kernel(const int* __restrict__ counts,
                            int* __restrict__ offsets,
                            int* __restrict__ cursors) {
  if (threadIdx.x == 0 && blockIdx.x == 0) {
    int s = 0;
    for (int e = 0; e < NEXP; ++e) { offsets[e] = s; cursors[e] = s; s += counts[e]; }
    offsets[NEXP] = s;
  }
}

// --------------------------- gather + fp32->bf16 ---------------------------
// One block per token: claim bucket slots for both experts, copy the row
// (converted to bf16) into both slots so expert GEMMs read contiguous A.
__global__ void gather_kernel(const float* __restrict__ x,
                              const int2* __restrict__ top_e,
                              const float2* __restrict__ top_w,
                              int* __restrict__ cursors,
                              int* __restrict__ bucket_tok,
                              float* __restrict__ bucket_w,
                              unsigned short* __restrict__ xg) {
  int t = blockIdx.x;
  __shared__ int rs[2];
  if (threadIdx.x == 0) {
    int2 e = top_e[t]; float2 w = top_w[t];
    int r0 = atomicAdd(&cursors[e.x], 1);
    int r1 = atomicAdd(&cursors[e.y], 1);
    bucket_tok[r0] = t; bucket_w[r0] = w.x;
    bucket_tok[r1] = t; bucket_w[r1] = w.y;
    rs[0] = r0; rs[1] = r1;
  }
  __syncthreads();
  int r0 = rs[0], r1 = rs[1];
  const f32x4* xr = (const f32x4*)(x + (size_t)t * HID);
  int i = threadIdx.x * 2;           // 256 threads * 8 elems = 2048
  f32x4 a = xr[i], b = xr[i + 1];
  short8 v;
  v[0] = (short)f2bf(a.x); v[1] = (short)f2bf(a.y);
  v[2] = (short)f2bf(a.z); v[3] = (short)f2bf(a.w);
  v[4] = (short)f2bf(b.x); v[5] = (short)f2bf(b.y);
  v[6] = (short)f2bf(b.z); v[7] = (short)f2bf(b.w);
  *(short8*)(xg + (size_t)r0 * HID + threadIdx.x * 8) = v;
  *(short8*)(xg + (size_t)r1 * HID + threadIdx.x * 8) = v;
}

// --------------------------- weight convert --------------------------------
__global__ void convert_kernel(const float* __restrict__ src,
                               unsigned short* __restrict__ dst, int n4) {
  int i = blockIdx.x * blockDim.x + threadIdx.x;
  if (i >= n4) return;
  f32x4 v = ((const f32x4*)src)[i];
  u16x4 o = {f2bf(v.x), f2bf(v.y), f2bf(v.z), f2bf(v.w)};
  ((u16x4*)dst)[i] = o;
}

// --------------------------- GEMM1: h = silu(x w1^T) * (x w3^T) ------------
// 128x128 tile, BK=64, 4 waves (2x2), dual-B sharing the A tile.
// LDS staged with global_load_lds(16B); XOR-swizzled source + swizzled
// ds_read (rule #21) to avoid the [128][64] row-major 16-way bank conflict.
__global__ __launch_bounds__(256) void gemm1_kernel(
    const unsigned short* __restrict__ xg,
    const unsigned short* __restrict__ wb1,
    const unsigned short* __restrict__ wb3,
    size_t wstride, int e0,
    unsigned short* __restrict__ h,
    const int* __restrict__ counts, const int* __restrict__ offsets) {
  int e   = e0 + blockIdx.z;
  int n_e = counts[e];
  int tm  = blockIdx.y;
  if (tm * 128 >= n_e) return;
  int off = offsets[e];
  int tn  = blockIdx.x;                       // 0..31 over FFN
  const unsigned short* b1 = wb1 + (size_t)blockIdx.z * wstride;
  const unsigned short* b3 = wb3 + (size_t)blockIdx.z * wstride;

  __shared__ __align__(16) unsigned short lds[3 * 128 * 64];
  unsigned short* lA  = lds;
  unsigned short* lB1 = lds + 8192;
  unsigned short* lB3 = lds + 16384;

  int tid = threadIdx.x, lane = tid & 63;
  int wv = tid >> 6, wm = wv >> 1, wn = wv & 1;

  const unsigned short* Abase  = xg + ((size_t)off + (size_t)tm * 128) * HID;
  const unsigned short* B1base = b1 + (size_t)tn * 128 * HID;
  const unsigned short* B3base = b3 + (size_t)tn * 128 * HID;

  f32x4 acc1[4][4], acc3[4][4];
#pragma unroll
  for (int i = 0; i < 4; ++i)
#pragma unroll
    for (int j = 0; j < 4; ++j) {
      acc1[i][j] = (f32x4){0.f, 0.f, 0.f, 0.f};
      acc3[i][j] = (f32x4){0.f, 0.f, 0.f, 0.f};
    }

  for (int kt = 0; kt < HID / 64; ++kt) {
    int k0 = kt * 64;
#pragma unroll
    for (int r = 0; r < 4; ++r) {
      int slot = r * 256 + tid;
      int row = slot >> 3, ch = slot & 7;
      int sch = ch ^ (row & 7);                       // pre-swizzled source
      size_t go = (size_t)row * HID + k0 + sch * 8;
      __builtin_amdgcn_global_load_lds(GPTR(Abase + go),  LPTR(lA + slot * 8),  16, 0, 0);
      __builtin_amdgcn_global_load_lds(GPTR(B1base + go), LPTR(lB1 + slot * 8), 16, 0, 0);
      __builtin_amdgcn_global_load_lds(GPTR(B3base + go), LPTR(lB3 + slot * 8), 16, 0, 0);
    }
    __syncthreads();
#pragma unroll
    for (int kk = 0; kk < 2; ++kk) {
      short8 af[4], bf1[4], bf3[4];
#pragma unroll
      for (int mf = 0; mf < 4; ++mf) {
        int row = wm * 64 + mf * 16 + (lane & 15);
        int ch  = kk * 4 + (lane >> 4);
        af[mf] = *(const short8*)(lA + row * 64 + (ch ^ (row & 7)) * 8);
      }
#pragma unroll
      for (int nf = 0; nf < 4; ++nf) {
        int row = wn * 64 + nf * 16 + (lane & 15);
        int ch  = kk * 4 + (lane >> 4);
        int ad  = row * 64 + (ch ^ (row & 7)) * 8;
        bf1[nf] = *(const short8*)(lB1 + ad);
        bf3[nf] = *(const short8*)(lB3 + ad);
      }
#pragma unroll
      for (int mf = 0; mf < 4; ++mf)
#pragma unroll
        for (int nf = 0; nf < 4; ++nf) {
          acc1[mf][nf] = __builtin_amdgcn_mfma_f32_16x16x32_bf16(af[mf], bf1[nf], acc1[mf][nf], 0, 0, 0);
          acc3[mf][nf] = __builtin_amdgcn_mfma_f32_16x16x32_bf16(af[mf], bf3[nf], acc3[mf][nf], 0, 0, 0);
        }
    }
    __syncthreads();
  }
  // epilogue: h = silu(c1) * c3, bf16
  int colbase = tn * 128 + wn * 64;
#pragma unroll
  for (int mf = 0; mf < 4; ++mf)
#pragma unroll
    for (int nf = 0; nf < 4; ++nf) {
      f32x4 c1 = acc1[mf][nf], c3 = acc3[mf][nf];
#pragma unroll
      for (int j = 0; j < 4; ++j) {
        int rl = tm * 128 + wm * 64 + mf * 16 + (lane >> 4) * 4 + j;
        if (rl < n_e) {
          int col = colbase + nf * 16 + (lane & 15);
          float a = c1[j];
          float s = a / (1.f + expf(-a)) * c3[j];
          h[((size_t)off + rl) * FFN_ + col] = f2bf(s);
        }
      }
    }
}

// --------------------------- GEMM2: out += w * (h w2^T) --------------------
__global__ __launch_bounds__(256) void gemm2_kernel(
    const unsigned short* __restrict__ h,
    const unsigned short* __restrict__ wb2,
    size_t wstride, int e0,
    const int* __restrict__ bucket_tok, const float* __restrict__ bucket_w,
    float* __restrict__ out,
    const int* __restrict__ counts, const int* __restrict__ offsets) {
  int e   = e0 + blockIdx.z;
  int n_e = counts[e];
  int tm  = blockIdx.y;
  if (tm * 128 >= n_e) return;
  int off = offsets[e];
  int tn  = blockIdx.x;                       // 0..15 over HID
  const unsigned short* b2 = wb2 + (size_t)blockIdx.z * wstride;

  __shared__ __align__(16) unsigned short lds[2 * 128 * 64];
  unsigned short* lA = lds;
  unsigned short* lB = lds + 8192;

  int tid = threadIdx.x, lane = tid & 63;
  int wv = tid >> 6, wm = wv >> 1, wn = wv & 1;

  const unsigned short* Abase = h  + ((size_t)off + (size_t)tm * 128) * FFN_;
  const unsigned short* Bbase = b2 + (size_t)tn * 128 * FFN_;

  f32x4 acc[4][4];
#pragma unroll
  for (int i = 0; i < 4; ++i)
#pragma unroll
    for (int j = 0; j < 4; ++j) acc[i][j] = (f32x4){0.f, 0.f, 0.f, 0.f};

  for (int kt = 0; kt < FFN_ / 64; ++kt) {
    int k0 = kt * 64;
#pragma unroll
    for (int r = 0; r < 4; ++r) {
      int slot = r * 256 + tid;
      int row = slot >> 3, ch = slot & 7;
      int sch = ch ^ (row & 7);
      size_t go = (size_t)row * FFN_ + k0 + sch * 8;
      __builtin_amdgcn_global_load_lds(GPTR(Abase + go), LPTR(lA + slot * 8), 16, 0, 0);
      __builtin_amdgcn_global_load_lds(GPTR(Bbase + go), LPTR(lB + slot * 8), 16, 0, 0);
    }
    __syncthreads();
#pragma unroll
    for (int kk = 0; kk < 2; ++kk) {
      short8 af[4], bf[4];
#pragma unroll
      for (int mf = 0; mf < 4; ++mf) {
        int row = wm * 64 + mf * 16 + (lane & 15);
        int ch  = kk * 4 + (lane >> 4);
        af[mf] = *(const short8*)(lA + row * 64 + (ch ^ (row & 7)) * 8);
      }
#pragma unroll
      for (int nf = 0; nf < 4; ++nf) {
        int row = wn * 64 + nf * 16 + (lane & 15);
        int ch  = kk * 4 + (lane >> 4);
        bf[nf] = *(const short8*)(lB + row * 64 + (ch ^ (row & 7)) * 8);
      }
#pragma unroll
      for (int mf = 0; mf < 4; ++mf)
#pragma unroll
        for (int nf = 0; nf < 4; ++nf)
          acc[mf][nf] = __builtin_amdgcn_mfma_f32_16x16x32_bf16(af[mf], bf[nf], acc[mf][nf], 0, 0, 0);
    }
    __syncthreads();
  }
  // epilogue: scaled atomic scatter into final output
  int colbase = tn * 128 + wn * 64;
#pragma unroll
  for (int mf = 0; mf < 4; ++mf)
#pragma unroll
    for (int nf = 0; nf < 4; ++nf) {
      f32x4 c = acc[mf][nf];
#pragma unroll
      for (int j = 0; j < 4; ++j) {
        int rl = tm * 128 + wm * 64 + mf * 16 + (lane >> 4) * 4 + j;
        if (rl < n_e) {
          int r   = off + rl;
          int col = colbase + nf * 16 + (lane & 15);
          float val = c[j] * bucket_w[r];
          atomicAdd(out + (size_t)bucket_tok[r] * HID + col, val);
        }
      }
    }
}

// --------------------------- launch ----------------------------------------
extern "C" void kernel_launch(void* const* d_in, const int* in_sizes, int n_in,
                              void* d_out, int out_size, void* d_ws, size_t ws_size,
                              hipStream_t stream) {
  const float* x  = (const float*)d_in[0];
  const float* gw = (const float*)d_in[1];
  const float* w1 = (const float*)d_in[2];
  const float* w3 = (const float*)d_in[3];
  const float* w2 = (const float*)d_in[4];
  float* out = (float*)d_out;
  int T = in_sizes[0] / HID;
  int R = 2 * T;                               // total bucket rows (= sum n_e)
  float* logits = out + (size_t)T * HID;

  uint8_t* p = (uint8_t*)d_ws;
  auto alloc = [&](size_t bytes) -> uint8_t* {
    uint8_t* q = p; p += (bytes + 255) & ~(size_t)255; return q;
  };
  int*    counts     = (int*)alloc(64);
  int*    cursors    = (int*)alloc(64);
  int*    offsets    = (int*)alloc(64);
  int2*   top_e      = (int2*)alloc((size_t)T * 8);
  float2* top_w      = (float2*)alloc((size_t)T * 8);
  int*    bucket_tok = (int*)alloc((size_t)R * 4);
  float*  bucket_w   = (float*)alloc((size_t)R * 4);
  unsigned short* xg = (unsigned short*)alloc((size_t)R * HID * 2);
  unsigned short* h  = (unsigned short*)alloc(((size_t)R + 128) * FFN_ * 2); // +pad for tile overread

  const size_t wsz1 = (size_t)FFN_ * HID;      // elems per expert weight matrix
  size_t used = (size_t)(p - (uint8_t*)d_ws);
  bool full = (used + 3 * NEXP * wsz1 * 2 + 4096 <= ws_size);

  hipMemsetAsync(d_out, 0, (size_t)T * HID * 4, stream);   // final accumulator
  hipMemsetAsync(counts, 0, 64, stream);

  router_kernel<<<(T + 3) / 4, 256, 0, stream>>>(x, gw, logits, top_e, top_w, counts, T);
  scan_kernel<<<1, 64, 0, stream>>>(counts, offsets, cursors);
  gather_kernel<<<T, 256, 0, stream>>>(x, top_e, top_w, cursors, bucket_tok, bucket_w, xg);

  int MT = (R + 127) / 128;                    // worst-case M tiles per expert
  if (full) {
    unsigned short* wb1 = (unsigned short*)alloc(NEXP * wsz1 * 2);
    unsigned short* wb3 = (unsigned short*)alloc(NEXP * wsz1 * 2);
    unsigned short* wb2 = (unsigned short*)alloc(NEXP * wsz1 * 2);
    int n4 = (int)(NEXP * wsz1 / 4);
    int cb = (n4 + 255) / 256;
    convert_kernel<<<cb, 256, 0, stream>>>(w1, wb1, n4);
    convert_kernel<<<cb, 256, 0, stream>>>(w3, wb3, n4);
    convert_kernel<<<cb, 256, 0, stream>>>(w2, wb2, n4);
    gemm1_kernel<<<dim3(FFN_ / 128, MT, NEXP), 256, 0, stream>>>(
        xg, wb1, wb3, wsz1, 0, h, counts, offsets);
    gemm2_kernel<<<dim3(HID / 128, MT, NEXP), 256, 0, stream>>>(
        h, wb2, wsz1, 0, bucket_tok, bucket_w, out, counts, offsets);
  } else {
    unsigned short* wb1 = (unsigned short*)alloc(wsz1 * 2);
    unsigned short* wb3 = (unsigned short*)alloc(wsz1 * 2);
    unsigned short* wb2 = (unsigned short*)alloc(wsz1 * 2);
    int n4 = (int)(wsz1 / 4);
    int cb = (n4 + 255) / 256;
    for (int e = 0; e < NEXP; ++e) {
      convert_kernel<<<cb, 256, 0, stream>>>(w1 + (size_t)e * wsz1, wb1, n4);
      convert_kernel<<<cb, 256, 0, stream>>>(w3 + (size_t)e * wsz1, wb3, n4);
      convert_kernel<<<cb, 256, 0, stream>>>(w2 + (size_t)e * wsz1, wb2, n4);
      gemm1_kernel<<<dim3(FFN_ / 128, MT, 1), 256, 0, stream>>>(
          xg, wb1, wb3, 0, e, h, counts, offsets);
      gemm2_kernel<<<dim3(HID / 128, MT, 1), 256, 0, stream>>>(
          h, wb2, 0, e, bucket_tok, bucket_w, out, counts, offsets);
    }
  }
}